// Round 10
// baseline (475.588 us; speedup 1.0000x reference)
//
#include <hip/hip_runtime.h>

constexpr int N_NODES = 50000;
constexpr int N_EDGES = 1600000;
constexpr int E_TOT   = N_EDGES + N_NODES;   // self-loops appended
constexpr int IN_DIM  = 128;
constexpr int HEADS   = 4;
constexpr int FDIM    = 64;
constexpr int HF      = 256;                  // HEADS * FDIM
constexpr float NEG   = 0.2f;
constexpr int NB_SCAN = (N_NODES + 255) / 256;  // 196 scan blocks

__device__ __forceinline__ float leaky(float t) {
    return fmaxf(t, 0.f) + NEG * fminf(t, 0.f);
}

__device__ __forceinline__ unsigned short f2bf(float f) {   // RNE bf16
    unsigned int u = __float_as_uint(f);
    u += 0x7fffu + ((u >> 16) & 1u);
    return (unsigned short)(u >> 16);
}
__device__ __forceinline__ float bf_lo(unsigned int u) {
    return __uint_as_float(u << 16);
}
__device__ __forceinline__ float bf_hi(unsigned int u) {
    return __uint_as_float(u & 0xffff0000u);
}

__device__ __forceinline__ int wave_incl_scan(int v, int lane) {
    #pragma unroll
    for (int off = 1; off < 64; off <<= 1) {
        int n = __shfl_up(v, off);
        if (lane >= off) v += n;
    }
    return v;
}

// ---- Kernel 1: h = x @ W, fused att logits; h stored as bf16 --------------
__global__ __launch_bounds__(256) void gemm_kernel(const float* __restrict__ x,
                                                   const float* __restrict__ W,
                                                   const float* __restrict__ att_src,
                                                   const float* __restrict__ att_dst,
                                                   unsigned short* __restrict__ h_bf,
                                                   float* __restrict__ a_s,
                                                   float* __restrict__ a_d) {
    __shared__ float xs[IN_DIM][64];   // 32 KB, xs[k][row]
    const int t = threadIdx.x;
    const int node0 = blockIdx.x * 64;

    {   // stage: thread t loads row (t&63), k-range (t>>6)*32 .. +31
        const int r  = t & 63;
        const int k0 = (t >> 6) * 32;
        int row = node0 + r;
        if (row >= N_NODES) row = N_NODES - 1;   // clamp (valid mem)
        const float4* src = reinterpret_cast<const float4*>(&x[row * IN_DIM + k0]);
        #pragma unroll
        for (int i = 0; i < 8; ++i) {
            float4 v = src[i];
            int k = k0 + i * 4;
            xs[k + 0][r] = v.x;
            xs[k + 1][r] = v.y;
            xs[k + 2][r] = v.z;
            xs[k + 3][r] = v.w;
        }
    }
    __syncthreads();

    const int l  = t & 63;          // lane
    const int c  = l * 4;           // output col
    const int rg = (t >> 6) * 16;   // row base (wave-uniform)
    float acc[16][4];
    #pragma unroll
    for (int r = 0; r < 16; ++r)
        #pragma unroll
        for (int j = 0; j < 4; ++j) acc[r][j] = 0.f;

    #pragma unroll 2
    for (int k = 0; k < IN_DIM; ++k) {
        const float4 wv = *reinterpret_cast<const float4*>(&W[k * HF + c]);
        const float4 xa = *reinterpret_cast<const float4*>(&xs[k][rg + 0]);
        const float4 xb = *reinterpret_cast<const float4*>(&xs[k][rg + 4]);
        const float4 xc = *reinterpret_cast<const float4*>(&xs[k][rg + 8]);
        const float4 xd = *reinterpret_cast<const float4*>(&xs[k][rg + 12]);
        const float xr[16] = {xa.x, xa.y, xa.z, xa.w, xb.x, xb.y, xb.z, xb.w,
                              xc.x, xc.y, xc.z, xc.w, xd.x, xd.y, xd.z, xd.w};
        #pragma unroll
        for (int r = 0; r < 16; ++r) {
            acc[r][0] = fmaf(xr[r], wv.x, acc[r][0]);
            acc[r][1] = fmaf(xr[r], wv.y, acc[r][1]);
            acc[r][2] = fmaf(xr[r], wv.z, acc[r][2]);
            acc[r][3] = fmaf(xr[r], wv.w, acc[r][3]);
        }
    }

    // att epilogue: per row, 16-lane dot-reduce (head = l>>4 matches col range)
    const float4 asv = *reinterpret_cast<const float4*>(&att_src[c]);
    const float4 adv = *reinterpret_cast<const float4*>(&att_dst[c]);
    #pragma unroll
    for (int r = 0; r < 16; ++r) {
        float ps = acc[r][0] * asv.x + acc[r][1] * asv.y +
                   acc[r][2] * asv.z + acc[r][3] * asv.w;
        float pd = acc[r][0] * adv.x + acc[r][1] * adv.y +
                   acc[r][2] * adv.z + acc[r][3] * adv.w;
        #pragma unroll
        for (int off = 1; off < 16; off <<= 1) {
            ps += __shfl_xor(ps, off);
            pd += __shfl_xor(pd, off);
        }
        const int node = node0 + rg + r;
        if ((l & 15) == 0 && node < N_NODES) {
            a_s[node * HEADS + (l >> 4)] = ps;
            a_d[node * HEADS + (l >> 4)] = pd;
        }
    }

    // bf16 store of h
    #pragma unroll
    for (int r = 0; r < 16; ++r) {
        const int node = node0 + rg + r;
        if (node < N_NODES) {
            ushort4 v;
            v.x = f2bf(acc[r][0]); v.y = f2bf(acc[r][1]);
            v.z = f2bf(acc[r][2]); v.w = f2bf(acc[r][3]);
            *reinterpret_cast<ushort4*>(&h_bf[node * HF + c]) = v;
        }
    }
}

// ---------------- Kernel 2: zero the degree counters ----------------
__global__ void zero_kernel(int* __restrict__ counts) {
    const int i = blockIdx.x * blockDim.x + threadIdx.x;
    if (i < N_NODES) counts[i] = 0;
}

// ---------------- Kernel 3: dst histogram ----------------
__global__ void hist_kernel(const int* __restrict__ ei, int* __restrict__ counts) {
    const int e = blockIdx.x * blockDim.x + threadIdx.x;
    if (e >= E_TOT) return;
    const int dst = (e < N_EDGES) ? ei[N_EDGES + e] : e - N_EDGES;
    atomicAdd(&counts[dst], 1);
}

// ---------------- Kernels 4a/4b/4c: two-level exclusive scan ----------------
__global__ __launch_bounds__(256) void scanA_kernel(const int* __restrict__ counts,
                                                    int* __restrict__ local,
                                                    int* __restrict__ bsum) {
    const int t = threadIdx.x, lane = t & 63, w = t >> 6;
    const int i = blockIdx.x * 256 + t;
    const int v = (i < N_NODES) ? counts[i] : 0;
    const int inc = wave_incl_scan(v, lane);
    __shared__ int wt[4];
    if (lane == 63) wt[w] = inc;
    __syncthreads();
    int base = 0;
    #pragma unroll
    for (int k = 0; k < 3; ++k) if (k < w) base += wt[k];
    if (i < N_NODES) local[i] = base + inc - v;       // block-local exclusive
    if (t == 255) bsum[blockIdx.x] = base + inc;      // block total
}

__global__ __launch_bounds__(256) void scanB_kernel(const int* __restrict__ bsum,
                                                    int* __restrict__ boff) {
    const int t = threadIdx.x, lane = t & 63, w = t >> 6;
    const int v = (t < NB_SCAN) ? bsum[t] : 0;
    const int inc = wave_incl_scan(v, lane);
    __shared__ int wt[4];
    if (lane == 63) wt[w] = inc;
    __syncthreads();
    int base = 0;
    #pragma unroll
    for (int k = 0; k < 3; ++k) if (k < w) base += wt[k];
    if (t < NB_SCAN) boff[t] = base + inc - v;        // exclusive block offset
}

__global__ __launch_bounds__(256) void scanC_kernel(const int* __restrict__ local,
                                                    const int* __restrict__ boff,
                                                    int* __restrict__ offsets,
                                                    int* __restrict__ cursor) {
    const int i = blockIdx.x * 256 + threadIdx.x;
    if (i < N_NODES) {
        const int o = local[i] + boff[blockIdx.x];
        offsets[i] = o;
        cursor[i]  = o;
    }
    if (i == 0) offsets[N_NODES] = E_TOT;
}

// ---------------- Kernel 5: fill CSR payload (src only) ----------------
__global__ void fill_kernel(const int* __restrict__ ei,
                            int* __restrict__ cursor,
                            int* __restrict__ sorted_src) {
    const int e = blockIdx.x * blockDim.x + threadIdx.x;
    if (e >= E_TOT) return;
    int src, dst;
    if (e < N_EDGES) { src = ei[e]; dst = ei[N_EDGES + e]; }
    else             { src = dst = e - N_EDGES; }
    const int slot = atomicAdd(&cursor[dst], 1);
    sorted_src[slot] = src;
}

// ---------------- Kernel 6: gather-aggregate, one wave per dst, 2 edges/round
// bf16 h rows are 512B -> 32 lanes per edge; half = lane>>5 picks edge j+half.
// lane (il=lane&31) covers feats il*8..il*8+7 (head = il>>3).
// ex recomputed inline (VALU was idle; saves the 26.4MB sorted_ex stream).
__global__ __launch_bounds__(256) void gather_kernel(const int* __restrict__ sorted_src,
                                                     const float* __restrict__ a_s,
                                                     const float* __restrict__ a_d,
                                                     const int* __restrict__ offsets,
                                                     const unsigned short* __restrict__ h_bf,
                                                     const float* __restrict__ bias,
                                                     float* __restrict__ out) {
    const int dst  = (blockIdx.x * 256 + threadIdx.x) >> 6;
    const int lane = threadIdx.x & 63;
    if (dst >= N_NODES) return;
    const int half = lane >> 5;
    const int il   = lane & 31;
    const int hd   = il >> 3;

    const int beg = __builtin_amdgcn_readfirstlane(offsets[dst]);
    const int end = __builtin_amdgcn_readfirstlane(offsets[dst + 1]);
    const float ad = a_d[dst * HEADS + hd];

    float a0 = 0.f, a1 = 0.f, a2 = 0.f, a3 = 0.f;
    float a4 = 0.f, a5 = 0.f, a6 = 0.f, a7 = 0.f;
    float dsum = 0.f;

    auto body = [&](int slot) {
        const int   src = sorted_src[slot];
        const float as  = a_s[src * HEADS + hd];
        const float ex  = expf(leaky(as + ad));
        const uint4 hv  = *reinterpret_cast<const uint4*>(&h_bf[src * HF + il * 8]);
        a0 = fmaf(ex, bf_lo(hv.x), a0); a1 = fmaf(ex, bf_hi(hv.x), a1);
        a2 = fmaf(ex, bf_lo(hv.y), a2); a3 = fmaf(ex, bf_hi(hv.y), a3);
        a4 = fmaf(ex, bf_lo(hv.z), a4); a5 = fmaf(ex, bf_hi(hv.z), a5);
        a6 = fmaf(ex, bf_lo(hv.w), a6); a7 = fmaf(ex, bf_hi(hv.w), a7);
        dsum += ex;
    };

    int j = beg;
    for (; j + 7 < end; j += 8) {        // 8 edges per iteration (4 per half)
        body(j + half);
        body(j + 2 + half);
        body(j + 4 + half);
        body(j + 6 + half);
    }
    for (; j + 1 < end; j += 2) body(j + half);
    if (j < end && half == 0) body(j);   // odd tail: half 0 only

    // combine the two halves (edge partition), per-head denominator included
    a0 += __shfl_xor(a0, 32); a1 += __shfl_xor(a1, 32);
    a2 += __shfl_xor(a2, 32); a3 += __shfl_xor(a3, 32);
    a4 += __shfl_xor(a4, 32); a5 += __shfl_xor(a5, 32);
    a6 += __shfl_xor(a6, 32); a7 += __shfl_xor(a7, 32);
    dsum += __shfl_xor(dsum, 32);

    const float inv = 1.f / (dsum + 1e-16f);
    const int eo = il * 8 + half * 4;    // element offset within row
    const float4 bv = *reinterpret_cast<const float4*>(&bias[eo]);
    float4 o;
    o.x = (half ? a4 : a0) * inv + bv.x;
    o.y = (half ? a5 : a1) * inv + bv.y;
    o.z = (half ? a6 : a2) * inv + bv.z;
    o.w = (half ? a7 : a3) * inv + bv.w;
    *reinterpret_cast<float4*>(&out[dst * HF + eo]) = o;
}

extern "C" void kernel_launch(void* const* d_in, const int* in_sizes, int n_in,
                              void* d_out, int out_size, void* d_ws, size_t ws_size,
                              hipStream_t stream) {
    const float* x       = (const float*)d_in[0];
    const int*   ei      = (const int*)d_in[1];   // [2, E]: src row then dst row
    const float* W       = (const float*)d_in[2];
    const float* att_src = (const float*)d_in[3];
    const float* att_dst = (const float*)d_in[4];
    const float* bias    = (const float*)d_in[5];
    float* out = (float*)d_out;

    char* ws = (char*)d_ws;
    unsigned short* h_bf = (unsigned short*)(ws);        // 25,600,000 B
    float*  a_s        = (float*) (ws + 25600000);       //    800,000 B
    float*  a_d        = (float*) (ws + 26400000);       //    800,000 B
    int*    counts     = (int*)   (ws + 27200000);       //    200,000 B
    int*    offsets    = (int*)   (ws + 27400000);       //    200,004 B
    int*    cursor     = (int*)   (ws + 27600016);       //    200,000 B
    int*    sorted_src = (int*)   (ws + 27800016);       //  6,600,000 B
    int*    local      = (int*)   (ws + 34400016);       //    200,000 B
    int*    bsum       = (int*)   (ws + 34600016);       //        784 B
    int*    boff       = (int*)   (ws + 34600800);       //        784 B → 34.8 MB total

    gemm_kernel<<<(N_NODES + 63) / 64, 256, 0, stream>>>(x, W, att_src, att_dst,
                                                         h_bf, a_s, a_d);
    zero_kernel<<<(N_NODES + 255) / 256, 256, 0, stream>>>(counts);
    hist_kernel<<<(E_TOT + 255) / 256, 256, 0, stream>>>(ei, counts);
    scanA_kernel<<<NB_SCAN, 256, 0, stream>>>(counts, local, bsum);
    scanB_kernel<<<1, 256, 0, stream>>>(bsum, boff);
    scanC_kernel<<<NB_SCAN, 256, 0, stream>>>(local, boff, offsets, cursor);
    fill_kernel<<<(E_TOT + 255) / 256, 256, 0, stream>>>(ei, cursor, sorted_src);
    const long total_threads = (long)N_NODES * 64;
    gather_kernel<<<(int)((total_threads + 255) / 256), 256, 0, stream>>>(
        sorted_src, a_s, a_d, offsets, h_bf, bias, out);
}

// Round 12
// 392.934 us; speedup vs baseline: 1.2103x; 1.2103x over previous
//
#include <hip/hip_runtime.h>

constexpr int N_NODES = 50000;
constexpr int N_EDGES = 1600000;
constexpr int E_TOT   = N_EDGES + N_NODES;   // self-loops appended
constexpr int IN_DIM  = 128;
constexpr int HEADS   = 4;
constexpr int FDIM    = 64;
constexpr int HF      = 256;                  // HEADS * FDIM
constexpr float NEG   = 0.2f;
constexpr int NB_SCAN = (N_NODES + 255) / 256;  // 196 scan blocks
constexpr int NPX     = (N_NODES + 7) / 8;      // 6250 dst nodes per XCD
constexpr int FILL_CH = 16384;                  // edges per fill slice
constexpr int FILL_K  = (E_TOT + FILL_CH - 1) / FILL_CH;  // 101 slices

__device__ __forceinline__ float leaky(float t) {
    return fmaxf(t, 0.f) + NEG * fminf(t, 0.f);
}

__device__ __forceinline__ unsigned short f2bf(float f) {   // RNE bf16
    unsigned int u = __float_as_uint(f);
    u += 0x7fffu + ((u >> 16) & 1u);
    return (unsigned short)(u >> 16);
}
__device__ __forceinline__ float bf_lo(unsigned int u) {
    return __uint_as_float(u << 16);
}
__device__ __forceinline__ float bf_hi(unsigned int u) {
    return __uint_as_float(u & 0xffff0000u);
}

__device__ __forceinline__ int wave_incl_scan(int v, int lane) {
    #pragma unroll
    for (int off = 1; off < 64; off <<= 1) {
        int n = __shfl_up(v, off);
        if (lane >= off) v += n;
    }
    return v;
}

// ---- Kernel 1: h = x @ W, fused att logits; h stored as bf16 --------------
__global__ __launch_bounds__(256) void gemm_kernel(const float* __restrict__ x,
                                                   const float* __restrict__ W,
                                                   const float* __restrict__ att_src,
                                                   const float* __restrict__ att_dst,
                                                   unsigned short* __restrict__ h_bf,
                                                   float* __restrict__ a_s,
                                                   float* __restrict__ a_d) {
    __shared__ float xs[IN_DIM][64];   // 32 KB, xs[k][row]
    const int t = threadIdx.x;
    const int node0 = blockIdx.x * 64;

    {   // stage: thread t loads row (t&63), k-range (t>>6)*32 .. +31
        const int r  = t & 63;
        const int k0 = (t >> 6) * 32;
        int row = node0 + r;
        if (row >= N_NODES) row = N_NODES - 1;   // clamp (valid mem)
        const float4* src = reinterpret_cast<const float4*>(&x[row * IN_DIM + k0]);
        #pragma unroll
        for (int i = 0; i < 8; ++i) {
            float4 v = src[i];
            int k = k0 + i * 4;
            xs[k + 0][r] = v.x;
            xs[k + 1][r] = v.y;
            xs[k + 2][r] = v.z;
            xs[k + 3][r] = v.w;
        }
    }
    __syncthreads();

    const int l  = t & 63;          // lane
    const int c  = l * 4;           // output col
    const int rg = (t >> 6) * 16;   // row base (wave-uniform)
    float acc[16][4];
    #pragma unroll
    for (int r = 0; r < 16; ++r)
        #pragma unroll
        for (int j = 0; j < 4; ++j) acc[r][j] = 0.f;

    #pragma unroll 2
    for (int k = 0; k < IN_DIM; ++k) {
        const float4 wv = *reinterpret_cast<const float4*>(&W[k * HF + c]);
        const float4 xa = *reinterpret_cast<const float4*>(&xs[k][rg + 0]);
        const float4 xb = *reinterpret_cast<const float4*>(&xs[k][rg + 4]);
        const float4 xc = *reinterpret_cast<const float4*>(&xs[k][rg + 8]);
        const float4 xd = *reinterpret_cast<const float4*>(&xs[k][rg + 12]);
        const float xr[16] = {xa.x, xa.y, xa.z, xa.w, xb.x, xb.y, xb.z, xb.w,
                              xc.x, xc.y, xc.z, xc.w, xd.x, xd.y, xd.z, xd.w};
        #pragma unroll
        for (int r = 0; r < 16; ++r) {
            acc[r][0] = fmaf(xr[r], wv.x, acc[r][0]);
            acc[r][1] = fmaf(xr[r], wv.y, acc[r][1]);
            acc[r][2] = fmaf(xr[r], wv.z, acc[r][2]);
            acc[r][3] = fmaf(xr[r], wv.w, acc[r][3]);
        }
    }

    // att epilogue: per row, 16-lane dot-reduce (head = l>>4 matches col range)
    const float4 asv = *reinterpret_cast<const float4*>(&att_src[c]);
    const float4 adv = *reinterpret_cast<const float4*>(&att_dst[c]);
    #pragma unroll
    for (int r = 0; r < 16; ++r) {
        float ps = acc[r][0] * asv.x + acc[r][1] * asv.y +
                   acc[r][2] * asv.z + acc[r][3] * asv.w;
        float pd = acc[r][0] * adv.x + acc[r][1] * adv.y +
                   acc[r][2] * adv.z + acc[r][3] * adv.w;
        #pragma unroll
        for (int off = 1; off < 16; off <<= 1) {
            ps += __shfl_xor(ps, off);
            pd += __shfl_xor(pd, off);
        }
        const int node = node0 + rg + r;
        if ((l & 15) == 0 && node < N_NODES) {
            a_s[node * HEADS + (l >> 4)] = ps;
            a_d[node * HEADS + (l >> 4)] = pd;
        }
    }

    // bf16 store of h
    #pragma unroll
    for (int r = 0; r < 16; ++r) {
        const int node = node0 + rg + r;
        if (node < N_NODES) {
            ushort4 v;
            v.x = f2bf(acc[r][0]); v.y = f2bf(acc[r][1]);
            v.z = f2bf(acc[r][2]); v.w = f2bf(acc[r][3]);
            *reinterpret_cast<ushort4*>(&h_bf[node * HF + c]) = v;
        }
    }
}

// ---------------- Kernel 2: zero the degree counters ----------------
__global__ void zero_kernel(int* __restrict__ counts) {
    const int i = blockIdx.x * blockDim.x + threadIdx.x;
    if (i < N_NODES) counts[i] = 0;
}

// ---------------- Kernel 3: dst histogram + per-edge rank capture ----------
__global__ void hist_kernel(const int* __restrict__ ei,
                            int* __restrict__ counts,
                            int* __restrict__ rank) {
    const int e = blockIdx.x * blockDim.x + threadIdx.x;
    if (e >= E_TOT) return;
    const int dst = (e < N_EDGES) ? ei[N_EDGES + e] : e - N_EDGES;
    rank[e] = atomicAdd(&counts[dst], 1);   // rank is a sequential stream write
}

// ---------------- Kernels 4a/4b/4c: two-level exclusive scan ----------------
__global__ __launch_bounds__(256) void scanA_kernel(const int* __restrict__ counts,
                                                    int* __restrict__ local,
                                                    int* __restrict__ bsum) {
    const int t = threadIdx.x, lane = t & 63, w = t >> 6;
    const int i = blockIdx.x * 256 + t;
    const int v = (i < N_NODES) ? counts[i] : 0;
    const int inc = wave_incl_scan(v, lane);
    __shared__ int wt[4];
    if (lane == 63) wt[w] = inc;
    __syncthreads();
    int base = 0;
    #pragma unroll
    for (int k = 0; k < 3; ++k) if (k < w) base += wt[k];
    if (i < N_NODES) local[i] = base + inc - v;       // block-local exclusive
    if (t == 255) bsum[blockIdx.x] = base + inc;      // block total
}

__global__ __launch_bounds__(256) void scanB_kernel(const int* __restrict__ bsum,
                                                    int* __restrict__ boff) {
    const int t = threadIdx.x, lane = t & 63, w = t >> 6;
    const int v = (t < NB_SCAN) ? bsum[t] : 0;
    const int inc = wave_incl_scan(v, lane);
    __shared__ int wt[4];
    if (lane == 63) wt[w] = inc;
    __syncthreads();
    int base = 0;
    #pragma unroll
    for (int k = 0; k < 3; ++k) if (k < w) base += wt[k];
    if (t < NB_SCAN) boff[t] = base + inc - v;        // exclusive block offset
}

__global__ __launch_bounds__(256) void scanC_kernel(const int* __restrict__ local,
                                                    const int* __restrict__ boff,
                                                    int* __restrict__ offsets) {
    const int i = blockIdx.x * 256 + threadIdx.x;
    if (i < N_NODES) offsets[i] = local[i] + boff[blockIdx.x];
    if (i == 0) offsets[N_NODES] = E_TOT;
}

// ---------------- Kernel 5: fill CSR payload — atomic-free, XCD-partitioned -
// Block (xcd = bid&7, slice = bid>>3): stream edge slice, handle only dsts in
// this XCD's range. sorted_src lines then belong to ONE XCD's L2 -> single
// writeback per line (kills the 15x write amplification seen in R10).
// Correct for ANY blockIdx->XCD mapping (each edge processed exactly once).
__global__ __launch_bounds__(256) void fill_kernel(const int* __restrict__ ei,
                                                   const int* __restrict__ rank,
                                                   const int* __restrict__ offsets,
                                                   int* __restrict__ sorted_src) {
    const int bid = blockIdx.x;
    const int lo  = (bid & 7) * NPX;            // dst range of this XCD
    const int hi  = min(N_NODES, lo + NPX);
    const int e0  = (bid >> 3) * FILL_CH;
    const int e1  = min(E_TOT, e0 + FILL_CH);
    for (int e = e0 + threadIdx.x; e < e1; e += 256) {
        const int dst = (e < N_EDGES) ? ei[N_EDGES + e] : e - N_EDGES;
        if (dst >= lo && dst < hi) {
            const int src = (e < N_EDGES) ? ei[e] : dst;
            sorted_src[offsets[dst] + rank[e]] = src;
        }
    }
}

// ---------------- Kernel 6: gather-aggregate, one wave per dst, 2 edges/round
// bf16 h rows are 512B -> 32 lanes per edge; half = lane>>5 picks edge j+half.
// lane (il=lane&31) covers feats il*8..il*8+7 (head = il>>3).
__global__ __launch_bounds__(256) void gather_kernel(const int* __restrict__ sorted_src,
                                                     const float* __restrict__ a_s,
                                                     const float* __restrict__ a_d,
                                                     const int* __restrict__ offsets,
                                                     const unsigned short* __restrict__ h_bf,
                                                     const float* __restrict__ bias,
                                                     float* __restrict__ out) {
    const int dst  = (blockIdx.x * 256 + threadIdx.x) >> 6;
    const int lane = threadIdx.x & 63;
    if (dst >= N_NODES) return;
    const int half = lane >> 5;
    const int il   = lane & 31;
    const int hd   = il >> 3;

    const int beg = __builtin_amdgcn_readfirstlane(offsets[dst]);
    const int end = __builtin_amdgcn_readfirstlane(offsets[dst + 1]);
    const float ad = a_d[dst * HEADS + hd];

    float a0 = 0.f, a1 = 0.f, a2 = 0.f, a3 = 0.f;
    float a4 = 0.f, a5 = 0.f, a6 = 0.f, a7 = 0.f;
    float dsum = 0.f;

    auto body = [&](int slot) {
        const int   src = sorted_src[slot];
        const float as  = a_s[src * HEADS + hd];
        const float ex  = expf(leaky(as + ad));
        const uint4 hv  = *reinterpret_cast<const uint4*>(&h_bf[src * HF + il * 8]);
        a0 = fmaf(ex, bf_lo(hv.x), a0); a1 = fmaf(ex, bf_hi(hv.x), a1);
        a2 = fmaf(ex, bf_lo(hv.y), a2); a3 = fmaf(ex, bf_hi(hv.y), a3);
        a4 = fmaf(ex, bf_lo(hv.z), a4); a5 = fmaf(ex, bf_hi(hv.z), a5);
        a6 = fmaf(ex, bf_lo(hv.w), a6); a7 = fmaf(ex, bf_hi(hv.w), a7);
        dsum += ex;
    };

    int j = beg;
    for (; j + 7 < end; j += 8) {        // 8 edges per iteration (4 per half)
        body(j + half);
        body(j + 2 + half);
        body(j + 4 + half);
        body(j + 6 + half);
    }
    for (; j + 1 < end; j += 2) body(j + half);
    if (j < end && half == 0) body(j);   // odd tail: half 0 only

    // combine the two halves (edge partition), per-head denominator included
    a0 += __shfl_xor(a0, 32); a1 += __shfl_xor(a1, 32);
    a2 += __shfl_xor(a2, 32); a3 += __shfl_xor(a3, 32);
    a4 += __shfl_xor(a4, 32); a5 += __shfl_xor(a5, 32);
    a6 += __shfl_xor(a6, 32); a7 += __shfl_xor(a7, 32);
    dsum += __shfl_xor(dsum, 32);

    const float inv = 1.f / (dsum + 1e-16f);
    const int eo = il * 8 + half * 4;    // element offset within row
    const float4 bv = *reinterpret_cast<const float4*>(&bias[eo]);
    float4 o;
    o.x = (half ? a4 : a0) * inv + bv.x;
    o.y = (half ? a5 : a1) * inv + bv.y;
    o.z = (half ? a6 : a2) * inv + bv.z;
    o.w = (half ? a7 : a3) * inv + bv.w;
    *reinterpret_cast<float4*>(&out[dst * HF + eo]) = o;
}

extern "C" void kernel_launch(void* const* d_in, const int* in_sizes, int n_in,
                              void* d_out, int out_size, void* d_ws, size_t ws_size,
                              hipStream_t stream) {
    const float* x       = (const float*)d_in[0];
    const int*   ei      = (const int*)d_in[1];   // [2, E]: src row then dst row
    const float* W       = (const float*)d_in[2];
    const float* att_src = (const float*)d_in[3];
    const float* att_dst = (const float*)d_in[4];
    const float* bias    = (const float*)d_in[5];
    float* out = (float*)d_out;

    char* ws = (char*)d_ws;
    unsigned short* h_bf = (unsigned short*)(ws);        // 25,600,000 B
    float*  a_s        = (float*) (ws + 25600000);       //    800,000 B
    float*  a_d        = (float*) (ws + 26400000);       //    800,000 B
    int*    counts     = (int*)   (ws + 27200000);       //    200,000 B
    int*    offsets    = (int*)   (ws + 27400000);       //    200,004 B
    int*    rank       = (int*)   (ws + 27600016);       //  6,600,000 B
    int*    sorted_src = (int*)   (ws + 34200016);       //  6,600,000 B
    int*    local      = (int*)   (ws + 40800016);       //    200,000 B
    int*    bsum       = (int*)   (ws + 41000016);       //        784 B
    int*    boff       = (int*)   (ws + 41000800);       //        784 B → 41 MB total

    gemm_kernel<<<(N_NODES + 63) / 64, 256, 0, stream>>>(x, W, att_src, att_dst,
                                                         h_bf, a_s, a_d);
    zero_kernel<<<(N_NODES + 255) / 256, 256, 0, stream>>>(counts);
    hist_kernel<<<(E_TOT + 255) / 256, 256, 0, stream>>>(ei, counts, rank);
    scanA_kernel<<<NB_SCAN, 256, 0, stream>>>(counts, local, bsum);
    scanB_kernel<<<1, 256, 0, stream>>>(bsum, boff);
    scanC_kernel<<<NB_SCAN, 256, 0, stream>>>(local, boff, offsets);
    fill_kernel<<<8 * FILL_K, 256, 0, stream>>>(ei, rank, offsets, sorted_src);
    const long total_threads = (long)N_NODES * 64;
    gather_kernel<<<(int)((total_threads + 255) / 256), 256, 0, stream>>>(
        sorted_src, a_s, a_d, offsets, h_bf, bias, out);
}